// Round 5
// baseline (1004.420 us; speedup 1.0000x reference)
//
#include <hip/hip_runtime.h>

typedef unsigned int uint;
typedef __attribute__((ext_vector_type(8))) short short8;   // 8 bf16 (4 VGPRs)
typedef __attribute__((ext_vector_type(4))) float f32x4;    // MFMA accumulator

#define N_NODES 100000
#define N_EDGES 1600000
#define NB_SCAN 391          // ceil(N_NODES/256)

// ---------------------------------------------------------------- bf16 helpers
__device__ __forceinline__ float bflo(uint v) { return __uint_as_float(v << 16); }
__device__ __forceinline__ float bfhi(uint v) { return __uint_as_float(v & 0xffff0000u); }
__device__ __forceinline__ uint packbf2(float a, float b) {   // RNE pack (a->lo, b->hi)
    uint ua = __float_as_uint(a), ub = __float_as_uint(b);
    ua += 0x7fffu + ((ua >> 16) & 1u);
    ub += 0x7fffu + ((ub >> 16) & 1u);
    return (ua >> 16) | (ub & 0xffff0000u);
}

// ---------------------------------------------------------------- graph prep

__global__ void deg_kernel(const int* __restrict__ dst, int* __restrict__ deg) {
    int e = blockIdx.x * blockDim.x + threadIdx.x;
    if (e < N_EDGES) atomicAdd(&deg[dst[e]], 1);
}

__global__ void scan_blocksum(const int* __restrict__ deg, int* __restrict__ blk) {
    __shared__ int s[256];
    int i = blockIdx.x * 256 + threadIdx.x;
    s[threadIdx.x] = (i < N_NODES) ? deg[i] : 0;
    __syncthreads();
    for (int off = 128; off > 0; off >>= 1) {
        if (threadIdx.x < off) s[threadIdx.x] += s[threadIdx.x + off];
        __syncthreads();
    }
    if (threadIdx.x == 0) blk[blockIdx.x] = s[0];
}

__global__ void scan_blockoff(int* __restrict__ blk, int* __restrict__ row_ptr_last) {
    __shared__ int s[512];
    int t = threadIdx.x;
    int v = (t < NB_SCAN) ? blk[t] : 0;
    s[t] = v;
    __syncthreads();
    for (int off = 1; off < 512; off <<= 1) {
        int xv = (t >= off) ? s[t - off] : 0;
        __syncthreads();
        s[t] += xv;
        __syncthreads();
    }
    if (t < NB_SCAN) blk[t] = s[t] - v;           // exclusive
    if (t == NB_SCAN - 1) *row_ptr_last = s[t];   // total = N_EDGES
}

__global__ void scan_final(const int* __restrict__ deg, const int* __restrict__ blk,
                           int* __restrict__ row_ptr, int* __restrict__ cursor) {
    __shared__ int s[256];
    int i = blockIdx.x * 256 + threadIdx.x;
    int v = (i < N_NODES) ? deg[i] : 0;
    s[threadIdx.x] = v;
    __syncthreads();
    for (int off = 1; off < 256; off <<= 1) {
        int xv = (threadIdx.x >= off) ? s[threadIdx.x - off] : 0;
        __syncthreads();
        s[threadIdx.x] += xv;
        __syncthreads();
    }
    if (i < N_NODES) {
        int ex = blk[blockIdx.x] + s[threadIdx.x] - v;
        row_ptr[i] = ex;
        cursor[i]  = ex;
    }
}

__global__ void fill_csr(const int* __restrict__ src, const int* __restrict__ dst,
                         int* __restrict__ cursor, int* __restrict__ colx) {
    int e = blockIdx.x * blockDim.x + threadIdx.x;
    if (e < N_EDGES) {
        int pos = atomicAdd(&cursor[dst[e]], 1);
        colx[pos] = src[e];
    }
}

__global__ void invdeg_kernel(const int* __restrict__ deg, float* __restrict__ invd) {
    int i = blockIdx.x * blockDim.x + threadIdx.x;
    if (i < N_NODES) invd[i] = 1.0f / fmaxf((float)deg[i], 1.0f);
}

// ---------------------------------------------------------------- transform
// out2[row][q] = packed bf16x2 of (relu(h*scale+shift)) or plain cast if scale==null.
__global__ void transform_bf16(const float* __restrict__ H,
                               const float* __restrict__ scale, const float* __restrict__ shift,
                               uint* __restrict__ out2) {
    int i = blockIdx.x * blockDim.x + threadIdx.x;
    if (i >= N_NODES * 32) return;
    int row = i >> 5, q = i & 31;
    float4 v = *(const float4*)(H + (size_t)row * 128 + q * 4);
    if (scale) {
        int c = q * 4;
        v.x = fmaxf(v.x * scale[c]     + shift[c],     0.f);
        v.y = fmaxf(v.y * scale[c + 1] + shift[c + 1], 0.f);
        v.z = fmaxf(v.z * scale[c + 2] + shift[c + 2], 0.f);
        v.w = fmaxf(v.w * scale[c + 3] + shift[c + 3], 0.f);
    }
    uint2 o;
    o.x = packbf2(v.x, v.y);
    o.y = packbf2(v.z, v.w);
    *(uint2*)(out2 + (size_t)row * 64 + q * 2) = o;
}

// ---------------------------------------------------------------- aggregation
__global__ void aggregate_bf16(const uint* __restrict__ H2,
                               const int* __restrict__ row_ptr, const int* __restrict__ colx,
                               const float* __restrict__ invd, uint* __restrict__ agg2) {
    int lane = threadIdx.x & 63;
    int node = blockIdx.x * 4 + (threadIdx.x >> 6);
    if (node >= N_NODES) return;
    int beg = row_ptr[node], end = row_ptr[node + 1];
    float a0 = 0.f, a1 = 0.f;
    int j = beg;
    for (; j + 4 <= end; j += 4) {
        int s0 = colx[j], s1 = colx[j + 1], s2 = colx[j + 2], s3 = colx[j + 3];
        uint v0 = H2[(size_t)s0 * 64 + lane];
        uint v1 = H2[(size_t)s1 * 64 + lane];
        uint v2 = H2[(size_t)s2 * 64 + lane];
        uint v3 = H2[(size_t)s3 * 64 + lane];
        a0 += bflo(v0) + bflo(v1) + bflo(v2) + bflo(v3);
        a1 += bfhi(v0) + bfhi(v1) + bfhi(v2) + bfhi(v3);
    }
    for (; j < end; ++j) {
        uint v = H2[(size_t)colx[j] * 64 + lane];
        a0 += bflo(v);
        a1 += bfhi(v);
    }
    float id = invd[node];
    agg2[(size_t)node * 64 + lane] = packbf2(a0 * id, a1 * id);
}

// ---------------------------------------------------------------- weight repack
// Wb fragment order: index = ((s*NT + c)*64 + lane)*4 + u, holding bf16 pair
// (k, k+1) where k = s*32 + (lane>>4)*8 + 2u, col = c*16 + (lane&15).
// k < 128 -> Wself[k][col], else Wneigh[k-128][col].
template <int OUTC>
__global__ void pack_weights(const float* __restrict__ Wself, const float* __restrict__ Wneigh,
                             uint* __restrict__ Wb) {
    constexpr int NT = OUTC / 16;
    int i = blockIdx.x * 256 + threadIdx.x;
    if (i >= 8 * NT * 64 * 4) return;
    int u = i & 3;
    int l = (i >> 2) & 63;
    int t = i >> 8;            // s*NT + c
    int c = t % NT, s = t / NT;
    int k = s * 32 + (l >> 4) * 8 + u * 2;
    int col = c * 16 + (l & 15);
    const float* W0 = (k < 128) ? (Wself + (size_t)k * OUTC)
                                : (Wneigh + (size_t)(k - 128) * OUTC);
    const float* W1 = (k + 1 < 128) ? (Wself + (size_t)(k + 1) * OUTC)
                                    : (Wneigh + (size_t)(k + 1 - 128) * OUTC);
    Wb[i] = packbf2(W0[col], W1[col]);
}

// ---------------------------------------------------------------- MFMA conv
// Out[r][c] = A[r] @ Wself + Agg[r] @ Wneigh + bias, via bf16 MFMA 16x16x32.
// Block = 4 waves, each wave computes 16 rows x OUTC. No LDS, no barriers.
// A-frag: lane holds row (lane&15), k-slice (lane>>4)*8..+7 -> one uint4.
// B-frag: prepacked in Wb (see pack_weights).
// D-frag: col = lane&15, row = (lane>>4)*4 + reg   [verified layout]
template <int OUTC, bool STATS>
__global__ __launch_bounds__(256) void conv_mfma(
    const uint* __restrict__ Aself2, const uint* __restrict__ Agg2,
    const uint* __restrict__ Wb, const float* __restrict__ bias,
    float* __restrict__ Out, float* __restrict__ stats) {
    constexpr int NT = OUTC / 16;
    const int lane = threadIdx.x & 63;
    const int wv   = threadIdx.x >> 6;
    const int row0 = blockIdx.x * 64 + wv * 16;
    const int arow = row0 + (lane & 15);
    const bool aok = arow < N_NODES;
    const int kq   = lane >> 4;      // 0..3

    f32x4 acc[NT];
#pragma unroll
    for (int c = 0; c < NT; ++c) acc[c] = (f32x4){0.f, 0.f, 0.f, 0.f};

    union U { uint4 u; short8 s; };

#pragma unroll
    for (int s = 0; s < 8; ++s) {
        const uint* Asrc = (s < 4) ? Aself2 : Agg2;
        U a;
        a.u = make_uint4(0u, 0u, 0u, 0u);
        if (aok) a.u = *(const uint4*)(Asrc + (size_t)arow * 64 + (s & 3) * 16 + kq * 4);
#pragma unroll
        for (int c = 0; c < NT; ++c) {
            U b;
            b.u = *(const uint4*)(Wb + ((size_t)(s * NT + c) * 64 + lane) * 4);
            acc[c] = __builtin_amdgcn_mfma_f32_16x16x32_bf16(a.s, b.s, acc[c], 0, 0, 0);
        }
    }

    // ---- epilogue: bias, guarded store, BN stats
    const int colbase = lane & 15;
#pragma unroll
    for (int c = 0; c < NT; ++c) {
        const int col = c * 16 + colbase;
        const float bv = bias[col];
        float sc = 0.f, qc = 0.f;
#pragma unroll
        for (int r = 0; r < 4; ++r) {
            int orow = row0 + kq * 4 + r;
            if (orow < N_NODES) {
                float v = acc[c][r] + bv;
                Out[(size_t)orow * OUTC + col] = v;
                if (STATS) { sc += v; qc += v * v; }
            }
        }
        if (STATS) {
            sc += __shfl_xor(sc, 16); sc += __shfl_xor(sc, 32);
            qc += __shfl_xor(qc, 16); qc += __shfl_xor(qc, 32);
            if (kq == 0) {
                atomicAdd(&stats[col], sc);
                atomicAdd(&stats[OUTC + col], qc);
            }
        }
    }
}

__global__ void bn_finalize(const float* __restrict__ stats,
                            const float* __restrict__ g, const float* __restrict__ be,
                            float* __restrict__ scale, float* __restrict__ shift) {
    int c = threadIdx.x;   // 128
    float mean = stats[c] * (1.0f / N_NODES);
    float var  = stats[128 + c] * (1.0f / N_NODES) - mean * mean;
    float inv  = rsqrtf(var + 1e-5f);
    float sc   = g[c] * inv;
    scale[c] = sc;
    shift[c] = be[c] - mean * sc;
}

__global__ void logsoftmax_k(float* __restrict__ out) {
    int lane = threadIdx.x & 63;
    int row = blockIdx.x * 4 + (threadIdx.x >> 6);
    if (row >= N_NODES) return;
    size_t base = (size_t)row * 64;
    float v = out[base + lane];
    float m = v;
#pragma unroll
    for (int o = 32; o > 0; o >>= 1) m = fmaxf(m, __shfl_xor(m, o));
    float e = expf(v - m);
    float ssum = e;
#pragma unroll
    for (int o = 32; o > 0; o >>= 1) ssum += __shfl_xor(ssum, o);
    out[base + lane] = v - m - logf(ssum);
}

// ---------------------------------------------------------------- launch

extern "C" void kernel_launch(void* const* d_in, const int* in_sizes, int n_in,
                              void* d_out, int out_size, void* d_ws, size_t ws_size,
                              hipStream_t stream) {
    const float* x   = (const float*)d_in[0];
    const int*   ei  = (const int*)d_in[1];
    const float* w0s = (const float*)d_in[2];
    const float* w0n = (const float*)d_in[3];
    const float* b0  = (const float*)d_in[4];
    const float* g0  = (const float*)d_in[5];
    const float* be0 = (const float*)d_in[6];
    const float* w1s = (const float*)d_in[7];
    const float* w1n = (const float*)d_in[8];
    const float* b1  = (const float*)d_in[9];
    const float* g1  = (const float*)d_in[10];
    const float* be1 = (const float*)d_in[11];
    const float* w2s = (const float*)d_in[12];
    const float* w2n = (const float*)d_in[13];
    const float* b2  = (const float*)d_in[14];
    float* out = (float*)d_out;

    const int* src = ei;            // edge_index[0]
    const int* dst = ei + N_EDGES;  // edge_index[1]

    char* w = (char*)d_ws;
    size_t off = 0;
    auto alloc = [&](size_t bytes) {
        void* p = w + off;
        off += (bytes + 255) & ~(size_t)255;
        return p;
    };
    int*   deg     = (int*)alloc(N_NODES * 4);
    int*   row_ptr = (int*)alloc((N_NODES + 1) * 4);
    int*   cursor  = (int*)alloc(N_NODES * 4);
    int*   blk     = (int*)alloc(512 * 4);
    int*   colx    = (int*)alloc((size_t)N_EDGES * 4);
    float* invd    = (float*)alloc(N_NODES * 4);
    float* stats   = (float*)alloc(256 * 4);
    float* scale0  = (float*)alloc(128 * 4);
    float* shift0  = (float*)alloc(128 * 4);
    float* scale1  = (float*)alloc(128 * 4);
    float* shift1  = (float*)alloc(128 * 4);
    uint*  wb0     = (uint*)alloc(16384 * 4);                  // layer0 packed W
    uint*  wb1     = (uint*)alloc(16384 * 4);                  // layer1 packed W
    uint*  wb2     = (uint*)alloc(8192 * 4);                   // layer2 packed W
    uint*  ht2     = (uint*)alloc((size_t)N_NODES * 64 * 4);   // packed bf16 features
    uint*  agg2    = (uint*)alloc((size_t)N_NODES * 64 * 4);   // packed bf16 aggregate
    float* h       = (float*)alloc((size_t)N_NODES * 128 * 4); // f32 conv output

    const int EB    = (N_EDGES + 255) / 256;      // 6250
    const int NBk   = NB_SCAN;                    // 391
    const int CONVG = (N_NODES + 63) / 64;        // 1563
    const int AGGG  = (N_NODES + 3) / 4;          // 25000
    const int TFG   = (N_NODES * 32 + 255) / 256; // 12500

    // graph prep + weight repack (independent of layer outputs)
    hipMemsetAsync(deg, 0, N_NODES * 4, stream);
    deg_kernel<<<EB, 256, 0, stream>>>(dst, deg);
    scan_blocksum<<<NBk, 256, 0, stream>>>(deg, blk);
    scan_blockoff<<<1, 512, 0, stream>>>(blk, row_ptr + N_NODES);
    scan_final<<<NBk, 256, 0, stream>>>(deg, blk, row_ptr, cursor);
    fill_csr<<<EB, 256, 0, stream>>>(src, dst, cursor, colx);
    invdeg_kernel<<<NBk, 256, 0, stream>>>(deg, invd);
    pack_weights<128><<<64, 256, 0, stream>>>(w0s, w0n, wb0);
    pack_weights<128><<<64, 256, 0, stream>>>(w1s, w1n, wb1);
    pack_weights<64><<<32, 256, 0, stream>>>(w2s, w2n, wb2);

    // layer 0: ht2 = bf16(x)
    transform_bf16<<<TFG, 256, 0, stream>>>(x, nullptr, nullptr, ht2);
    aggregate_bf16<<<AGGG, 256, 0, stream>>>(ht2, row_ptr, colx, invd, agg2);
    hipMemsetAsync(stats, 0, 256 * 4, stream);
    conv_mfma<128, true><<<CONVG, 256, 0, stream>>>(ht2, agg2, wb0, b0, h, stats);
    bn_finalize<<<1, 128, 0, stream>>>(stats, g0, be0, scale0, shift0);

    // layer 1: ht2 = bf16(relu(bn(h)))
    transform_bf16<<<TFG, 256, 0, stream>>>(h, scale0, shift0, ht2);
    aggregate_bf16<<<AGGG, 256, 0, stream>>>(ht2, row_ptr, colx, invd, agg2);
    hipMemsetAsync(stats, 0, 256 * 4, stream);
    conv_mfma<128, true><<<CONVG, 256, 0, stream>>>(ht2, agg2, wb1, b1, h, stats);
    bn_finalize<<<1, 128, 0, stream>>>(stats, g1, be1, scale1, shift1);

    // layer 2 + log_softmax
    transform_bf16<<<TFG, 256, 0, stream>>>(h, scale1, shift1, ht2);
    aggregate_bf16<<<AGGG, 256, 0, stream>>>(ht2, row_ptr, colx, invd, agg2);
    conv_mfma<64, false><<<CONVG, 256, 0, stream>>>(ht2, agg2, wb2, b2, out, nullptr);
    logsoftmax_k<<<AGGG, 256, 0, stream>>>(out);
}

// Round 8
// 579.814 us; speedup vs baseline: 1.7323x; 1.7323x over previous
//
#include <hip/hip_runtime.h>

typedef unsigned int uint;
typedef __attribute__((ext_vector_type(8))) short short8;   // 8 bf16 (4 VGPRs)
typedef __attribute__((ext_vector_type(4))) float f32x4;    // MFMA accumulator

#define N_NODES 100000
#define N_EDGES 1600000
#define NB_SCAN 391          // ceil(N_NODES/256)
#define CONVG_N 1563         // ceil(N_NODES/64)

// ---------------------------------------------------------------- bf16 helpers
__device__ __forceinline__ float bflo(uint v) { return __uint_as_float(v << 16); }
__device__ __forceinline__ float bfhi(uint v) { return __uint_as_float(v & 0xffff0000u); }
__device__ __forceinline__ uint packbf2(float a, float b) {   // RNE pack (a->lo, b->hi)
    uint ua = __float_as_uint(a), ub = __float_as_uint(b);
    ua += 0x7fffu + ((ua >> 16) & 1u);
    ub += 0x7fffu + ((ub >> 16) & 1u);
    return (ua >> 16) | (ub & 0xffff0000u);
}

// ---------------------------------------------------------------- graph prep

__global__ void deg_kernel(const int* __restrict__ dst, int* __restrict__ deg) {
    int e = blockIdx.x * blockDim.x + threadIdx.x;
    if (e < N_EDGES) atomicAdd(&deg[dst[e]], 1);
}

__global__ void scan_blocksum(const int* __restrict__ deg, int* __restrict__ blk) {
    __shared__ int s[256];
    int i = blockIdx.x * 256 + threadIdx.x;
    s[threadIdx.x] = (i < N_NODES) ? deg[i] : 0;
    __syncthreads();
    for (int off = 128; off > 0; off >>= 1) {
        if (threadIdx.x < off) s[threadIdx.x] += s[threadIdx.x + off];
        __syncthreads();
    }
    if (threadIdx.x == 0) blk[blockIdx.x] = s[0];
}

__global__ void scan_blockoff(int* __restrict__ blk, int* __restrict__ row_ptr_last) {
    __shared__ int s[512];
    int t = threadIdx.x;
    int v = (t < NB_SCAN) ? blk[t] : 0;
    s[t] = v;
    __syncthreads();
    for (int off = 1; off < 512; off <<= 1) {
        int xv = (t >= off) ? s[t - off] : 0;
        __syncthreads();
        s[t] += xv;
        __syncthreads();
    }
    if (t < NB_SCAN) blk[t] = s[t] - v;           // exclusive
    if (t == NB_SCAN - 1) *row_ptr_last = s[t];   // total = N_EDGES
}

__global__ void scan_final(const int* __restrict__ deg, const int* __restrict__ blk,
                           int* __restrict__ row_ptr, int* __restrict__ cursor) {
    __shared__ int s[256];
    int i = blockIdx.x * 256 + threadIdx.x;
    int v = (i < N_NODES) ? deg[i] : 0;
    s[threadIdx.x] = v;
    __syncthreads();
    for (int off = 1; off < 256; off <<= 1) {
        int xv = (threadIdx.x >= off) ? s[threadIdx.x - off] : 0;
        __syncthreads();
        s[threadIdx.x] += xv;
        __syncthreads();
    }
    if (i < N_NODES) {
        int ex = blk[blockIdx.x] + s[threadIdx.x] - v;
        row_ptr[i] = ex;
        cursor[i]  = ex;
    }
}

__global__ void fill_csr(const int* __restrict__ src, const int* __restrict__ dst,
                         int* __restrict__ cursor, int* __restrict__ colx) {
    int e = blockIdx.x * blockDim.x + threadIdx.x;
    if (e < N_EDGES) {
        int pos = atomicAdd(&cursor[dst[e]], 1);
        colx[pos] = src[e];
    }
}

__global__ void invdeg_kernel(const int* __restrict__ deg, float* __restrict__ invd) {
    int i = blockIdx.x * blockDim.x + threadIdx.x;
    if (i < N_NODES) invd[i] = 1.0f / fmaxf((float)deg[i], 1.0f);
}

// ---------------------------------------------------------------- transform
// out2[row][q] = packed bf16x2 of (relu(h*scale+shift)) or plain cast if scale==null.
__global__ void transform_bf16(const float* __restrict__ H,
                               const float* __restrict__ scale, const float* __restrict__ shift,
                               uint* __restrict__ out2) {
    int i = blockIdx.x * blockDim.x + threadIdx.x;
    if (i >= N_NODES * 32) return;
    int row = i >> 5, q = i & 31;
    float4 v = *(const float4*)(H + (size_t)row * 128 + q * 4);
    if (scale) {
        int c = q * 4;
        v.x = fmaxf(v.x * scale[c]     + shift[c],     0.f);
        v.y = fmaxf(v.y * scale[c + 1] + shift[c + 1], 0.f);
        v.z = fmaxf(v.z * scale[c + 2] + shift[c + 2], 0.f);
        v.w = fmaxf(v.w * scale[c + 3] + shift[c + 3], 0.f);
    }
    uint2 o;
    o.x = packbf2(v.x, v.y);
    o.y = packbf2(v.z, v.w);
    *(uint2*)(out2 + (size_t)row * 64 + q * 2) = o;
}

// ---------------------------------------------------------------- aggregation
// one wave per node; lane holds channels (2*lane, 2*lane+1) packed.
// unroll-8 over neighbors: latency-bound gather, maximize loads in flight.
__global__ void aggregate_bf16(const uint* __restrict__ H2,
                               const int* __restrict__ row_ptr, const int* __restrict__ colx,
                               const float* __restrict__ invd, uint* __restrict__ agg2) {
    int lane = threadIdx.x & 63;
    int node = blockIdx.x * 4 + (threadIdx.x >> 6);
    if (node >= N_NODES) return;
    int beg = row_ptr[node], end = row_ptr[node + 1];
    float a0 = 0.f, a1 = 0.f;
    int j = beg;
    for (; j + 8 <= end; j += 8) {
        int s0 = colx[j],     s1 = colx[j + 1], s2 = colx[j + 2], s3 = colx[j + 3];
        int s4 = colx[j + 4], s5 = colx[j + 5], s6 = colx[j + 6], s7 = colx[j + 7];
        uint v0 = H2[(size_t)s0 * 64 + lane];
        uint v1 = H2[(size_t)s1 * 64 + lane];
        uint v2 = H2[(size_t)s2 * 64 + lane];
        uint v3 = H2[(size_t)s3 * 64 + lane];
        uint v4 = H2[(size_t)s4 * 64 + lane];
        uint v5 = H2[(size_t)s5 * 64 + lane];
        uint v6 = H2[(size_t)s6 * 64 + lane];
        uint v7 = H2[(size_t)s7 * 64 + lane];
        a0 += (bflo(v0) + bflo(v1)) + (bflo(v2) + bflo(v3))
            + (bflo(v4) + bflo(v5)) + (bflo(v6) + bflo(v7));
        a1 += (bfhi(v0) + bfhi(v1)) + (bfhi(v2) + bfhi(v3))
            + (bfhi(v4) + bfhi(v5)) + (bfhi(v6) + bfhi(v7));
    }
    for (; j + 4 <= end; j += 4) {
        int s0 = colx[j], s1 = colx[j + 1], s2 = colx[j + 2], s3 = colx[j + 3];
        uint v0 = H2[(size_t)s0 * 64 + lane];
        uint v1 = H2[(size_t)s1 * 64 + lane];
        uint v2 = H2[(size_t)s2 * 64 + lane];
        uint v3 = H2[(size_t)s3 * 64 + lane];
        a0 += (bflo(v0) + bflo(v1)) + (bflo(v2) + bflo(v3));
        a1 += (bfhi(v0) + bfhi(v1)) + (bfhi(v2) + bfhi(v3));
    }
    for (; j < end; ++j) {
        uint v = H2[(size_t)colx[j] * 64 + lane];
        a0 += bflo(v);
        a1 += bfhi(v);
    }
    float id = invd[node];
    agg2[(size_t)node * 64 + lane] = packbf2(a0 * id, a1 * id);
}

// ---------------------------------------------------------------- weight repack
// Wb fragment order: index = ((s*NT + c)*64 + lane)*4 + u, holding bf16 pair
// (k, k+1) where k = s*32 + (lane>>4)*8 + 2u, col = c*16 + (lane&15).
// k < 128 -> Wself[k][col], else Wneigh[k-128][col].
template <int OUTC>
__global__ void pack_weights(const float* __restrict__ Wself, const float* __restrict__ Wneigh,
                             uint* __restrict__ Wb) {
    constexpr int NT = OUTC / 16;
    int i = blockIdx.x * 256 + threadIdx.x;
    if (i >= 8 * NT * 64 * 4) return;
    int u = i & 3;
    int l = (i >> 2) & 63;
    int t = i >> 8;            // s*NT + c
    int c = t % NT, s = t / NT;
    int k = s * 32 + (l >> 4) * 8 + u * 2;
    int col = c * 16 + (l & 15);
    const float* W0 = (k < 128) ? (Wself + (size_t)k * OUTC)
                                : (Wneigh + (size_t)(k - 128) * OUTC);
    const float* W1 = (k + 1 < 128) ? (Wself + (size_t)(k + 1) * OUTC)
                                    : (Wneigh + (size_t)(k + 1 - 128) * OUTC);
    Wb[i] = packbf2(W0[col], W1[col]);
}

// ---------------------------------------------------------------- MFMA conv
// Out[r][c] = A[r] @ Wself + Agg[r] @ Wneigh + bias, via bf16 MFMA 16x16x32.
// Block = 4 waves, each wave computes 16 rows x OUTC.
// A-frag: lane holds row (lane&15), k-slice (lane>>4)*8..+7 -> one uint4.
// B-frag: prepacked in Wb. D-frag: col = lane&15, row = (lane>>4)*4 + reg.
// BN stats: per-wave shfl reduce -> LDS cross-wave reduce -> ONE coalesced
// per-block partial row (NO global atomics — the r5 atomic convoy was the
// 253us stall: 1.6M device-scope f32 RMWs onto 256 addresses).
template <int OUTC, bool STATS>
__global__ __launch_bounds__(256) void conv_mfma(
    const uint* __restrict__ Aself2, const uint* __restrict__ Agg2,
    const uint* __restrict__ Wb, const float* __restrict__ bias,
    float* __restrict__ Out, float* __restrict__ Ppart) {
    constexpr int NT = OUTC / 16;
    __shared__ float red[4][2 * OUTC];
    const int lane = threadIdx.x & 63;
    const int wv   = threadIdx.x >> 6;
    const int row0 = blockIdx.x * 64 + wv * 16;
    const int arow = row0 + (lane & 15);
    const bool aok = arow < N_NODES;
    const int kq   = lane >> 4;      // 0..3

    f32x4 acc[NT];
#pragma unroll
    for (int c = 0; c < NT; ++c) acc[c] = (f32x4){0.f, 0.f, 0.f, 0.f};

    union U { uint4 u; short8 s; };

#pragma unroll
    for (int s = 0; s < 8; ++s) {
        const uint* Asrc = (s < 4) ? Aself2 : Agg2;
        U a;
        a.u = make_uint4(0u, 0u, 0u, 0u);
        if (aok) a.u = *(const uint4*)(Asrc + (size_t)arow * 64 + (s & 3) * 16 + kq * 4);
#pragma unroll
        for (int c = 0; c < NT; ++c) {
            U b;
            b.u = *(const uint4*)(Wb + ((size_t)(s * NT + c) * 64 + lane) * 4);
            acc[c] = __builtin_amdgcn_mfma_f32_16x16x32_bf16(a.s, b.s, acc[c], 0, 0, 0);
        }
    }

    // ---- epilogue: bias, guarded store, BN partial sums
    const int colbase = lane & 15;
#pragma unroll
    for (int c = 0; c < NT; ++c) {
        const int col = c * 16 + colbase;
        const float bv = bias[col];
        float sc = 0.f, qc = 0.f;
#pragma unroll
        for (int r = 0; r < 4; ++r) {
            int orow = row0 + kq * 4 + r;
            if (orow < N_NODES) {
                float v = acc[c][r] + bv;
                Out[(size_t)orow * OUTC + col] = v;
                if (STATS) { sc += v; qc += v * v; }
            }
        }
        if (STATS) {
            sc += __shfl_xor(sc, 16); sc += __shfl_xor(sc, 32);
            qc += __shfl_xor(qc, 16); qc += __shfl_xor(qc, 32);
            if (kq == 0) {
                red[wv][col]        = sc;
                red[wv][OUTC + col] = qc;
            }
        }
    }
    if (STATS) {
        __syncthreads();
        int t = threadIdx.x;
        if (t < 2 * OUTC) {
            float p = red[0][t] + red[1][t] + red[2][t] + red[3][t];
            Ppart[(size_t)blockIdx.x * (2 * OUTC) + t] = p;
        }
    }
}

// Sum Ppart[CONVG_N][2*OUTC] into stats[2*OUTC]. 32 blocks -> 32 atomics/address.
template <int OUTC>
__global__ void bn_reduce(const float* __restrict__ Ppart, float* __restrict__ stats) {
    int t = threadIdx.x;    // 0..2*OUTC-1
    float s = 0.f;
    for (int r = blockIdx.x; r < CONVG_N; r += gridDim.x)
        s += Ppart[(size_t)r * (2 * OUTC) + t];
    atomicAdd(&stats[t], s);
}

__global__ void bn_finalize(const float* __restrict__ stats,
                            const float* __restrict__ g, const float* __restrict__ be,
                            float* __restrict__ scale, float* __restrict__ shift) {
    int c = threadIdx.x;   // 128
    float mean = stats[c] * (1.0f / N_NODES);
    float var  = stats[128 + c] * (1.0f / N_NODES) - mean * mean;
    float inv  = rsqrtf(var + 1e-5f);
    float sc   = g[c] * inv;
    scale[c] = sc;
    shift[c] = be[c] - mean * sc;
}

__global__ void logsoftmax_k(float* __restrict__ out) {
    int lane = threadIdx.x & 63;
    int row = blockIdx.x * 4 + (threadIdx.x >> 6);
    if (row >= N_NODES) return;
    size_t base = (size_t)row * 64;
    float v = out[base + lane];
    float m = v;
#pragma unroll
    for (int o = 32; o > 0; o >>= 1) m = fmaxf(m, __shfl_xor(m, o));
    float e = expf(v - m);
    float ssum = e;
#pragma unroll
    for (int o = 32; o > 0; o >>= 1) ssum += __shfl_xor(ssum, o);
    out[base + lane] = v - m - logf(ssum);
}

// ---------------------------------------------------------------- launch

extern "C" void kernel_launch(void* const* d_in, const int* in_sizes, int n_in,
                              void* d_out, int out_size, void* d_ws, size_t ws_size,
                              hipStream_t stream) {
    const float* x   = (const float*)d_in[0];
    const int*   ei  = (const int*)d_in[1];
    const float* w0s = (const float*)d_in[2];
    const float* w0n = (const float*)d_in[3];
    const float* b0  = (const float*)d_in[4];
    const float* g0  = (const float*)d_in[5];
    const float* be0 = (const float*)d_in[6];
    const float* w1s = (const float*)d_in[7];
    const float* w1n = (const float*)d_in[8];
    const float* b1  = (const float*)d_in[9];
    const float* g1  = (const float*)d_in[10];
    const float* be1 = (const float*)d_in[11];
    const float* w2s = (const float*)d_in[12];
    const float* w2n = (const float*)d_in[13];
    const float* b2  = (const float*)d_in[14];
    float* out = (float*)d_out;

    const int* src = ei;            // edge_index[0]
    const int* dst = ei + N_EDGES;  // edge_index[1]

    char* w = (char*)d_ws;
    size_t off = 0;
    auto alloc = [&](size_t bytes) {
        void* p = w + off;
        off += (bytes + 255) & ~(size_t)255;
        return p;
    };
    int*   deg     = (int*)alloc(N_NODES * 4);
    int*   row_ptr = (int*)alloc((N_NODES + 1) * 4);
    int*   cursor  = (int*)alloc(N_NODES * 4);
    int*   blk     = (int*)alloc(512 * 4);
    int*   colx    = (int*)alloc((size_t)N_EDGES * 4);
    float* invd    = (float*)alloc(N_NODES * 4);
    float* stats   = (float*)alloc(256 * 4);
    float* scale0  = (float*)alloc(128 * 4);
    float* shift0  = (float*)alloc(128 * 4);
    float* scale1  = (float*)alloc(128 * 4);
    float* shift1  = (float*)alloc(128 * 4);
    uint*  wb0     = (uint*)alloc(16384 * 4);                  // layer0 packed W
    uint*  wb1     = (uint*)alloc(16384 * 4);                  // layer1 packed W
    uint*  wb2     = (uint*)alloc(8192 * 4);                   // layer2 packed W
    float* ppart   = (float*)alloc((size_t)CONVG_N * 256 * 4); // BN per-block partials
    uint*  ht2     = (uint*)alloc((size_t)N_NODES * 64 * 4);   // packed bf16 features
    uint*  agg2    = (uint*)alloc((size_t)N_NODES * 64 * 4);   // packed bf16 aggregate
    float* h       = (float*)alloc((size_t)N_NODES * 128 * 4); // f32 conv output

    const int EB    = (N_EDGES + 255) / 256;      // 6250
    const int NBk   = NB_SCAN;                    // 391
    const int CONVG = CONVG_N;                    // 1563
    const int AGGG  = (N_NODES + 3) / 4;          // 25000
    const int TFG   = (N_NODES * 32 + 255) / 256; // 12500

    // graph prep + weight repack (independent of layer outputs)
    hipMemsetAsync(deg, 0, N_NODES * 4, stream);
    deg_kernel<<<EB, 256, 0, stream>>>(dst, deg);
    scan_blocksum<<<NBk, 256, 0, stream>>>(deg, blk);
    scan_blockoff<<<1, 512, 0, stream>>>(blk, row_ptr + N_NODES);
    scan_final<<<NBk, 256, 0, stream>>>(deg, blk, row_ptr, cursor);
    fill_csr<<<EB, 256, 0, stream>>>(src, dst, cursor, colx);
    invdeg_kernel<<<NBk, 256, 0, stream>>>(deg, invd);
    pack_weights<128><<<64, 256, 0, stream>>>(w0s, w0n, wb0);
    pack_weights<128><<<64, 256, 0, stream>>>(w1s, w1n, wb1);
    pack_weights<64><<<32, 256, 0, stream>>>(w2s, w2n, wb2);

    // layer 0: ht2 = bf16(x)
    transform_bf16<<<TFG, 256, 0, stream>>>(x, nullptr, nullptr, ht2);
    aggregate_bf16<<<AGGG, 256, 0, stream>>>(ht2, row_ptr, colx, invd, agg2);
    conv_mfma<128, true><<<CONVG, 256, 0, stream>>>(ht2, agg2, wb0, b0, h, ppart);
    hipMemsetAsync(stats, 0, 256 * 4, stream);
    bn_reduce<128><<<32, 256, 0, stream>>>(ppart, stats);
    bn_finalize<<<1, 128, 0, stream>>>(stats, g0, be0, scale0, shift0);

    // layer 1: ht2 = bf16(relu(bn(h)))
    transform_bf16<<<TFG, 256, 0, stream>>>(h, scale0, shift0, ht2);
    aggregate_bf16<<<AGGG, 256, 0, stream>>>(ht2, row_ptr, colx, invd, agg2);
    conv_mfma<128, true><<<CONVG, 256, 0, stream>>>(ht2, agg2, wb1, b1, h, ppart);
    hipMemsetAsync(stats, 0, 256 * 4, stream);
    bn_reduce<128><<<32, 256, 0, stream>>>(ppart, stats);
    bn_finalize<<<1, 128, 0, stream>>>(stats, g1, be1, scale1, shift1);

    // layer 2 + log_softmax
    transform_bf16<<<TFG, 256, 0, stream>>>(h, scale1, shift1, ht2);
    aggregate_bf16<<<AGGG, 256, 0, stream>>>(ht2, row_ptr, colx, invd, agg2);
    conv_mfma<64, false><<<CONVG, 256, 0, stream>>>(ht2, agg2, wb2, b2, out, nullptr);
    logsoftmax_k<<<AGGG, 256, 0, stream>>>(out);
}

// Round 9
// 484.247 us; speedup vs baseline: 2.0742x; 1.1974x over previous
//
#include <hip/hip_runtime.h>

typedef unsigned int uint;
typedef __attribute__((ext_vector_type(8))) short short8;   // 8 bf16 (4 VGPRs)
typedef __attribute__((ext_vector_type(4))) float f32x4;    // MFMA accumulator

#define N_NODES 100000
#define N_EDGES 1600000
#define NB_SCAN 391          // ceil(N_NODES/256)
#define CONVG_N 1563         // ceil(N_NODES/64)

// ---------------------------------------------------------------- bf16 helpers
__device__ __forceinline__ float bflo(uint v) { return __uint_as_float(v << 16); }
__device__ __forceinline__ float bfhi(uint v) { return __uint_as_float(v & 0xffff0000u); }
__device__ __forceinline__ uint packbf2(float a, float b) {   // RNE pack (a->lo, b->hi)
    uint ua = __float_as_uint(a), ub = __float_as_uint(b);
    ua += 0x7fffu + ((ua >> 16) & 1u);
    ub += 0x7fffu + ((ub >> 16) & 1u);
    return (ua >> 16) | (ub & 0xffff0000u);
}

// ---------------------------------------------------------------- graph prep
// Degree count + rank assignment in ONE atomic pass: rank[e] = position of
// edge e within its dst bucket. (r8: fill_csr's 130us was 1.6M contended
// atomic-with-return + dependent scatter; deg already did the same atomics
// fire-and-forget. Fusing halves total contended atomics and makes the fill
// pass atomic-free.)
__global__ void deg_rank_kernel(const int* __restrict__ dst,
                                int* __restrict__ deg, int* __restrict__ rank) {
    int e = blockIdx.x * blockDim.x + threadIdx.x;
    if (e < N_EDGES) rank[e] = atomicAdd(&deg[dst[e]], 1);
}

__global__ void scan_blocksum(const int* __restrict__ deg, int* __restrict__ blk) {
    __shared__ int s[256];
    int i = blockIdx.x * 256 + threadIdx.x;
    s[threadIdx.x] = (i < N_NODES) ? deg[i] : 0;
    __syncthreads();
    for (int off = 128; off > 0; off >>= 1) {
        if (threadIdx.x < off) s[threadIdx.x] += s[threadIdx.x + off];
        __syncthreads();
    }
    if (threadIdx.x == 0) blk[blockIdx.x] = s[0];
}

__global__ void scan_blockoff(int* __restrict__ blk, int* __restrict__ row_ptr_last) {
    __shared__ int s[512];
    int t = threadIdx.x;
    int v = (t < NB_SCAN) ? blk[t] : 0;
    s[t] = v;
    __syncthreads();
    for (int off = 1; off < 512; off <<= 1) {
        int xv = (t >= off) ? s[t - off] : 0;
        __syncthreads();
        s[t] += xv;
        __syncthreads();
    }
    if (t < NB_SCAN) blk[t] = s[t] - v;           // exclusive
    if (t == NB_SCAN - 1) *row_ptr_last = s[t];   // total = N_EDGES
}

__global__ void scan_final(const int* __restrict__ deg, const int* __restrict__ blk,
                           int* __restrict__ row_ptr) {
    __shared__ int s[256];
    int i = blockIdx.x * 256 + threadIdx.x;
    int v = (i < N_NODES) ? deg[i] : 0;
    s[threadIdx.x] = v;
    __syncthreads();
    for (int off = 1; off < 256; off <<= 1) {
        int xv = (threadIdx.x >= off) ? s[threadIdx.x - off] : 0;
        __syncthreads();
        s[threadIdx.x] += xv;
        __syncthreads();
    }
    if (i < N_NODES) row_ptr[i] = blk[blockIdx.x] + s[threadIdx.x] - v;
}

// Atomic-free CSR fill: pos = row_ptr[dst] (L2-resident 400KB table) + rank.
__global__ void fill_csr2(const int* __restrict__ src, const int* __restrict__ dst,
                          const int* __restrict__ row_ptr, const int* __restrict__ rank,
                          int* __restrict__ colx) {
    int e = blockIdx.x * blockDim.x + threadIdx.x;
    if (e < N_EDGES) colx[row_ptr[dst[e]] + rank[e]] = src[e];
}

__global__ void invdeg_kernel(const int* __restrict__ deg, float* __restrict__ invd) {
    int i = blockIdx.x * blockDim.x + threadIdx.x;
    if (i < N_NODES) invd[i] = 1.0f / fmaxf((float)deg[i], 1.0f);
}

// ---------------------------------------------------------------- transform
// out2[row][q] = packed bf16x2 of (relu(h*scale+shift)) or plain cast if scale==null.
__global__ void transform_bf16(const float* __restrict__ H,
                               const float* __restrict__ scale, const float* __restrict__ shift,
                               uint* __restrict__ out2) {
    int i = blockIdx.x * blockDim.x + threadIdx.x;
    if (i >= N_NODES * 32) return;
    int row = i >> 5, q = i & 31;
    float4 v = *(const float4*)(H + (size_t)row * 128 + q * 4);
    if (scale) {
        int c = q * 4;
        v.x = fmaxf(v.x * scale[c]     + shift[c],     0.f);
        v.y = fmaxf(v.y * scale[c + 1] + shift[c + 1], 0.f);
        v.z = fmaxf(v.z * scale[c + 2] + shift[c + 2], 0.f);
        v.w = fmaxf(v.w * scale[c + 3] + shift[c + 3], 0.f);
    }
    uint2 o;
    o.x = packbf2(v.x, v.y);
    o.y = packbf2(v.z, v.w);
    *(uint2*)(out2 + (size_t)row * 64 + q * 2) = o;
}

// ---------------------------------------------------------------- aggregation
// one wave per node; lane holds channels (2*lane, 2*lane+1) packed.
// unroll-8 over neighbors: latency-bound gather, maximize loads in flight.
__global__ void aggregate_bf16(const uint* __restrict__ H2,
                               const int* __restrict__ row_ptr, const int* __restrict__ colx,
                               const float* __restrict__ invd, uint* __restrict__ agg2) {
    int lane = threadIdx.x & 63;
    int node = blockIdx.x * 4 + (threadIdx.x >> 6);
    if (node >= N_NODES) return;
    int beg = row_ptr[node], end = row_ptr[node + 1];
    float a0 = 0.f, a1 = 0.f;
    int j = beg;
    for (; j + 8 <= end; j += 8) {
        int s0 = colx[j],     s1 = colx[j + 1], s2 = colx[j + 2], s3 = colx[j + 3];
        int s4 = colx[j + 4], s5 = colx[j + 5], s6 = colx[j + 6], s7 = colx[j + 7];
        uint v0 = H2[(size_t)s0 * 64 + lane];
        uint v1 = H2[(size_t)s1 * 64 + lane];
        uint v2 = H2[(size_t)s2 * 64 + lane];
        uint v3 = H2[(size_t)s3 * 64 + lane];
        uint v4 = H2[(size_t)s4 * 64 + lane];
        uint v5 = H2[(size_t)s5 * 64 + lane];
        uint v6 = H2[(size_t)s6 * 64 + lane];
        uint v7 = H2[(size_t)s7 * 64 + lane];
        a0 += (bflo(v0) + bflo(v1)) + (bflo(v2) + bflo(v3))
            + (bflo(v4) + bflo(v5)) + (bflo(v6) + bflo(v7));
        a1 += (bfhi(v0) + bfhi(v1)) + (bfhi(v2) + bfhi(v3))
            + (bfhi(v4) + bfhi(v5)) + (bfhi(v6) + bfhi(v7));
    }
    for (; j + 4 <= end; j += 4) {
        int s0 = colx[j], s1 = colx[j + 1], s2 = colx[j + 2], s3 = colx[j + 3];
        uint v0 = H2[(size_t)s0 * 64 + lane];
        uint v1 = H2[(size_t)s1 * 64 + lane];
        uint v2 = H2[(size_t)s2 * 64 + lane];
        uint v3 = H2[(size_t)s3 * 64 + lane];
        a0 += (bflo(v0) + bflo(v1)) + (bflo(v2) + bflo(v3));
        a1 += (bfhi(v0) + bfhi(v1)) + (bfhi(v2) + bfhi(v3));
    }
    for (; j < end; ++j) {
        uint v = H2[(size_t)colx[j] * 64 + lane];
        a0 += bflo(v);
        a1 += bfhi(v);
    }
    float id = invd[node];
    agg2[(size_t)node * 64 + lane] = packbf2(a0 * id, a1 * id);
}

// ---------------------------------------------------------------- weight repack
// Wb fragment order: index = ((s*NT + c)*64 + lane)*4 + u, holding bf16 pair
// (k, k+1) where k = s*32 + (lane>>4)*8 + 2u, col = c*16 + (lane&15).
// k < 128 -> Wself[k][col], else Wneigh[k-128][col].
template <int OUTC>
__global__ void pack_weights(const float* __restrict__ Wself, const float* __restrict__ Wneigh,
                             uint* __restrict__ Wb) {
    constexpr int NT = OUTC / 16;
    int i = blockIdx.x * 256 + threadIdx.x;
    if (i >= 8 * NT * 64 * 4) return;
    int u = i & 3;
    int l = (i >> 2) & 63;
    int t = i >> 8;            // s*NT + c
    int c = t % NT, s = t / NT;
    int k = s * 32 + (l >> 4) * 8 + u * 2;
    int col = c * 16 + (l & 15);
    const float* W0 = (k < 128) ? (Wself + (size_t)k * OUTC)
                                : (Wneigh + (size_t)(k - 128) * OUTC);
    const float* W1 = (k + 1 < 128) ? (Wself + (size_t)(k + 1) * OUTC)
                                    : (Wneigh + (size_t)(k + 1 - 128) * OUTC);
    Wb[i] = packbf2(W0[col], W1[col]);
}

// ---------------------------------------------------------------- MFMA conv
// Out[r][c] = A[r] @ Wself + Agg[r] @ Wneigh + bias, via bf16 MFMA 16x16x32.
// Block = 4 waves, each wave computes 16 rows x OUTC.
// A-frag: lane holds row (lane&15), k-slice (lane>>4)*8..+7 -> one uint4.
// B-frag: prepacked in Wb. D-frag: col = lane&15, row = (lane>>4)*4 + reg.
// BN stats: per-wave shfl reduce -> LDS cross-wave reduce -> ONE coalesced
// per-block partial row (no global atomics).
template <int OUTC, bool STATS>
__global__ __launch_bounds__(256) void conv_mfma(
    const uint* __restrict__ Aself2, const uint* __restrict__ Agg2,
    const uint* __restrict__ Wb, const float* __restrict__ bias,
    float* __restrict__ Out, float* __restrict__ Ppart) {
    constexpr int NT = OUTC / 16;
    __shared__ float red[4][2 * OUTC];
    const int lane = threadIdx.x & 63;
    const int wv   = threadIdx.x >> 6;
    const int row0 = blockIdx.x * 64 + wv * 16;
    const int arow = row0 + (lane & 15);
    const bool aok = arow < N_NODES;
    const int kq   = lane >> 4;      // 0..3

    f32x4 acc[NT];
#pragma unroll
    for (int c = 0; c < NT; ++c) acc[c] = (f32x4){0.f, 0.f, 0.f, 0.f};

    union U { uint4 u; short8 s; };

#pragma unroll
    for (int s = 0; s < 8; ++s) {
        const uint* Asrc = (s < 4) ? Aself2 : Agg2;
        U a;
        a.u = make_uint4(0u, 0u, 0u, 0u);
        if (aok) a.u = *(const uint4*)(Asrc + (size_t)arow * 64 + (s & 3) * 16 + kq * 4);
#pragma unroll
        for (int c = 0; c < NT; ++c) {
            U b;
            b.u = *(const uint4*)(Wb + ((size_t)(s * NT + c) * 64 + lane) * 4);
            acc[c] = __builtin_amdgcn_mfma_f32_16x16x32_bf16(a.s, b.s, acc[c], 0, 0, 0);
        }
    }

    // ---- epilogue: bias, guarded store, BN partial sums
    const int colbase = lane & 15;
#pragma unroll
    for (int c = 0; c < NT; ++c) {
        const int col = c * 16 + colbase;
        const float bv = bias[col];
        float sc = 0.f, qc = 0.f;
#pragma unroll
        for (int r = 0; r < 4; ++r) {
            int orow = row0 + kq * 4 + r;
            if (orow < N_NODES) {
                float v = acc[c][r] + bv;
                Out[(size_t)orow * OUTC + col] = v;
                if (STATS) { sc += v; qc += v * v; }
            }
        }
        if (STATS) {
            sc += __shfl_xor(sc, 16); sc += __shfl_xor(sc, 32);
            qc += __shfl_xor(qc, 16); qc += __shfl_xor(qc, 32);
            if (kq == 0) {
                red[wv][col]        = sc;
                red[wv][OUTC + col] = qc;
            }
        }
    }
    if (STATS) {
        __syncthreads();
        int t = threadIdx.x;
        if (t < 2 * OUTC) {
            float p = red[0][t] + red[1][t] + red[2][t] + red[3][t];
            Ppart[(size_t)blockIdx.x * (2 * OUTC) + t] = p;
        }
    }
}

// Sum Ppart[CONVG_N][2*OUTC] into stats[2*OUTC]. 32 blocks -> 32 atomics/address.
template <int OUTC>
__global__ void bn_reduce(const float* __restrict__ Ppart, float* __restrict__ stats) {
    int t = threadIdx.x;    // 0..2*OUTC-1
    float s = 0.f;
    for (int r = blockIdx.x; r < CONVG_N; r += gridDim.x)
        s += Ppart[(size_t)r * (2 * OUTC) + t];
    atomicAdd(&stats[t], s);
}

__global__ void bn_finalize(const float* __restrict__ stats,
                            const float* __restrict__ g, const float* __restrict__ be,
                            float* __restrict__ scale, float* __restrict__ shift) {
    int c = threadIdx.x;   // 128
    float mean = stats[c] * (1.0f / N_NODES);
    float var  = stats[128 + c] * (1.0f / N_NODES) - mean * mean;
    float inv  = rsqrtf(var + 1e-5f);
    float sc   = g[c] * inv;
    scale[c] = sc;
    shift[c] = be[c] - mean * sc;
}

__global__ void logsoftmax_k(float* __restrict__ out) {
    int lane = threadIdx.x & 63;
    int row = blockIdx.x * 4 + (threadIdx.x >> 6);
    if (row >= N_NODES) return;
    size_t base = (size_t)row * 64;
    float v = out[base + lane];
    float m = v;
#pragma unroll
    for (int o = 32; o > 0; o >>= 1) m = fmaxf(m, __shfl_xor(m, o));
    float e = expf(v - m);
    float ssum = e;
#pragma unroll
    for (int o = 32; o > 0; o >>= 1) ssum += __shfl_xor(ssum, o);
    out[base + lane] = v - m - logf(ssum);
}

// ---------------------------------------------------------------- launch

extern "C" void kernel_launch(void* const* d_in, const int* in_sizes, int n_in,
                              void* d_out, int out_size, void* d_ws, size_t ws_size,
                              hipStream_t stream) {
    const float* x   = (const float*)d_in[0];
    const int*   ei  = (const int*)d_in[1];
    const float* w0s = (const float*)d_in[2];
    const float* w0n = (const float*)d_in[3];
    const float* b0  = (const float*)d_in[4];
    const float* g0  = (const float*)d_in[5];
    const float* be0 = (const float*)d_in[6];
    const float* w1s = (const float*)d_in[7];
    const float* w1n = (const float*)d_in[8];
    const float* b1  = (const float*)d_in[9];
    const float* g1  = (const float*)d_in[10];
    const float* be1 = (const float*)d_in[11];
    const float* w2s = (const float*)d_in[12];
    const float* w2n = (const float*)d_in[13];
    const float* b2  = (const float*)d_in[14];
    float* out = (float*)d_out;

    const int* src = ei;            // edge_index[0]
    const int* dst = ei + N_EDGES;  // edge_index[1]

    char* w = (char*)d_ws;
    size_t off = 0;
    auto alloc = [&](size_t bytes) {
        void* p = w + off;
        off += (bytes + 255) & ~(size_t)255;
        return p;
    };
    int*   deg     = (int*)alloc(N_NODES * 4);
    int*   row_ptr = (int*)alloc((N_NODES + 1) * 4);
    int*   blk     = (int*)alloc(512 * 4);
    int*   colx    = (int*)alloc((size_t)N_EDGES * 4);
    float* invd    = (float*)alloc(N_NODES * 4);
    float* stats   = (float*)alloc(256 * 4);
    float* scale0  = (float*)alloc(128 * 4);
    float* shift0  = (float*)alloc(128 * 4);
    float* scale1  = (float*)alloc(128 * 4);
    float* shift1  = (float*)alloc(128 * 4);
    uint*  wb0     = (uint*)alloc(16384 * 4);                  // layer0 packed W
    uint*  wb1     = (uint*)alloc(16384 * 4);                  // layer1 packed W
    uint*  wb2     = (uint*)alloc(8192 * 4);                   // layer2 packed W
    float* ppart   = (float*)alloc((size_t)CONVG_N * 256 * 4); // BN per-block partials
    uint*  ht2     = (uint*)alloc((size_t)N_NODES * 64 * 4);   // packed bf16 features
    uint*  agg2    = (uint*)alloc((size_t)N_NODES * 64 * 4);   // packed bf16 aggregate
    float* h       = (float*)alloc((size_t)N_NODES * 128 * 4); // f32 conv output
    // rank[e] aliases h: rank's last use (fill_csr2) precedes h's first write
    // (conv_mfma layer 0) -> no extra workspace needed.
    int*   rank    = (int*)h;

    const int EB    = (N_EDGES + 255) / 256;      // 6250
    const int NBk   = NB_SCAN;                    // 391
    const int CONVG = CONVG_N;                    // 1563
    const int AGGG  = (N_NODES + 3) / 4;          // 25000
    const int TFG   = (N_NODES * 32 + 255) / 256; // 12500

    // graph prep + weight repack (independent of layer outputs)
    hipMemsetAsync(deg, 0, N_NODES * 4, stream);
    deg_rank_kernel<<<EB, 256, 0, stream>>>(dst, deg, rank);
    scan_blocksum<<<NBk, 256, 0, stream>>>(deg, blk);
    scan_blockoff<<<1, 512, 0, stream>>>(blk, row_ptr + N_NODES);
    scan_final<<<NBk, 256, 0, stream>>>(deg, blk, row_ptr);
    fill_csr2<<<EB, 256, 0, stream>>>(src, dst, row_ptr, rank, colx);
    invdeg_kernel<<<NBk, 256, 0, stream>>>(deg, invd);
    pack_weights<128><<<64, 256, 0, stream>>>(w0s, w0n, wb0);
    pack_weights<128><<<64, 256, 0, stream>>>(w1s, w1n, wb1);
    pack_weights<64><<<32, 256, 0, stream>>>(w2s, w2n, wb2);

    // layer 0: ht2 = bf16(x)
    transform_bf16<<<TFG, 256, 0, stream>>>(x, nullptr, nullptr, ht2);
    aggregate_bf16<<<AGGG, 256, 0, stream>>>(ht2, row_ptr, colx, invd, agg2);
    conv_mfma<128, true><<<CONVG, 256, 0, stream>>>(ht2, agg2, wb0, b0, h, ppart);
    hipMemsetAsync(stats, 0, 256 * 4, stream);
    bn_reduce<128><<<32, 256, 0, stream>>>(ppart, stats);
    bn_finalize<<<1, 128, 0, stream>>>(stats, g0, be0, scale0, shift0);

    // layer 1: ht2 = bf16(relu(bn(h)))
    transform_bf16<<<TFG, 256, 0, stream>>>(h, scale0, shift0, ht2);
    aggregate_bf16<<<AGGG, 256, 0, stream>>>(ht2, row_ptr, colx, invd, agg2);
    conv_mfma<128, true><<<CONVG, 256, 0, stream>>>(ht2, agg2, wb1, b1, h, ppart);
    hipMemsetAsync(stats, 0, 256 * 4, stream);
    bn_reduce<128><<<32, 256, 0, stream>>>(ppart, stats);
    bn_finalize<<<1, 128, 0, stream>>>(stats, g1, be1, scale1, shift1);

    // layer 2 + log_softmax
    transform_bf16<<<TFG, 256, 0, stream>>>(h, scale1, shift1, ht2);
    aggregate_bf16<<<AGGG, 256, 0, stream>>>(ht2, row_ptr, colx, invd, agg2);
    conv_mfma<64, false><<<CONVG, 256, 0, stream>>>(ht2, agg2, wb2, b2, out, nullptr);
    logsoftmax_k<<<AGGG, 256, 0, stream>>>(out);
}